// Round 1
// baseline (15380.582 us; speedup 1.0000x reference)
//
#include <hip/hip_runtime.h>
#include <stdint.h>

// Persistent-kernel autoregressive decode for Generator_18124761989654.
// Key reductions vs reference: batch-0 only; rows 0..tok-1 only; cross-attn
// collapsed to rank-1 form (kappa/U/C tables); final block computed for the
// single needed row; logits v-sliced across 128 WGs with packed atomicMax.

#define NWG 128
#define NT 256

__device__ __forceinline__ float wredsum(float v){
#pragma unroll
  for (int m=32;m;m>>=1) v += __shfl_xor(v,m,64);
  return v;
}
__device__ __forceinline__ float wredmax(float v){
#pragma unroll
  for (int m=32;m;m>>=1) v = fmaxf(v,__shfl_xor(v,m,64));
  return v;
}
// reduce within aligned 32-thread group (halves of a wave)
__device__ __forceinline__ float g32sum(float v){
#pragma unroll
  for (int m=16;m;m>>=1) v += __shfl_xor(v,m,64);
  return v;
}
__device__ __forceinline__ float g32max(float v){
#pragma unroll
  for (int m=16;m;m>>=1) v = fmaxf(v,__shfl_xor(v,m,64));
  return v;
}
__device__ __forceinline__ unsigned long long shflx64(unsigned long long v,int m){
  unsigned int lo=(unsigned int)(v&0xffffffffull), hi=(unsigned int)(v>>32);
  lo=__shfl_xor(lo,m,64); hi=__shfl_xor(hi,m,64);
  return (((unsigned long long)hi)<<32)|(unsigned long long)lo;
}

__device__ __forceinline__ float pe_val(int l, int e){
  int j = e >> 1;
  // matches np: float32( -log(10000.)/256 ) = -0.03597789207803197
  float dv = expf((float)(2*j) * (-0.035977892078031970f));
  float arg = (float)l * dv;
  return (e & 1) ? cosf(arg) : sinf(arg);
}

// epoch grid barrier; equality test => safe with 0xAA-poisoned flags (negative int)
__device__ void gbar(int* arr, int* rel, int ep){
  __syncthreads();
  if (threadIdx.x==0){
    __threadfence();
    __hip_atomic_store(arr + blockIdx.x*16, ep, __ATOMIC_RELEASE, __HIP_MEMORY_SCOPE_AGENT);
  }
  if (blockIdx.x==0){
    if (threadIdx.x < NWG){
      while (__hip_atomic_load(arr + threadIdx.x*16, __ATOMIC_ACQUIRE, __HIP_MEMORY_SCOPE_AGENT) != ep)
        __builtin_amdgcn_s_sleep(1);
    }
    __syncthreads();
    if (threadIdx.x==0){
      __hip_atomic_store(rel, ep, __ATOMIC_RELEASE, __HIP_MEMORY_SCOPE_AGENT);
    }
  }
  if (threadIdx.x==0){
    while (__hip_atomic_load(rel, __ATOMIC_ACQUIRE, __HIP_MEMORY_SCOPE_AGENT) != ep)
      __builtin_amdgcn_s_sleep(1);
    __threadfence();
  }
  __syncthreads();
}

extern "C" __global__ __launch_bounds__(256, 2)
void gen18124_kernel(const float* __restrict__ noise,
                     const float* __restrict__ iw, const float* __restrict__ ib,
                     const float* __restrict__ Wq, const float* __restrict__ bq,
                     const float* __restrict__ Wk, const float* __restrict__ bk,
                     const float* __restrict__ Wv, const float* __restrict__ bv,
                     const float* __restrict__ Wo, const float* __restrict__ bo,
                     const float* __restrict__ lng, const float* __restrict__ lnb,
                     const float* __restrict__ emb, const float* __restrict__ sw,
                     const float* __restrict__ sb,
                     int* __restrict__ out, float* __restrict__ ws)
{
  const float ISQ = 0.17677669529663687f; // 1/sqrt(32)
  __shared__ float sm[5376];
  __shared__ unsigned long long redU[4];

  // ---- workspace layout (floats) ----
  float* WVEC = ws;            // 64
  float* SKC  = ws+64;         // [2][256] colsum(Wk)
  float* SVC  = ws+576;        // [2][256] colsum(Wv)
  float* KAP  = ws+1088;       // [2][8][256]
  float* UT   = ws+5184;       // [2][8][256]
  float* CC   = ws+9280;       // [2][256]
  float* BETA = ws+9792;       // [2][8]
  unsigned long long* SLOT = (unsigned long long*)(ws+9808);
  int* ARR = (int*)(ws+9824);  // 128 * stride16 ints
  int* REL = (int*)(ws+11872);
  float* Yg  = ws+11876;       // [64][256]
  float* R1  = ws+28260;       // [64][256]
  float* QB  = ws+44644;       // [64][256]
  float* KB  = ws+61028;       // [64][256]
  float* VB  = ws+77412;       // [64][256]
  float* R2  = ws+93796;       // [64][256]
  float* Z2P = ws+110180;      // [8][64][256]
  float* Z3P = ws+241252;      // [8][256]

  const int g = blockIdx.x, t = threadIdx.x;
  int ep = 0;

  // ================= Prelude A: colsums, wvec, Y0, slot/out init =================
  {
    int c0 = 2*g;
    float a0=Wk[t*256+c0],       a1=Wk[t*256+c0+1];
    float a2=Wk[65536+t*256+c0], a3=Wk[65536+t*256+c0+1];
    float a4=Wv[t*256+c0],       a5=Wv[t*256+c0+1];
    float a6=Wv[65536+t*256+c0], a7=Wv[65536+t*256+c0+1];
    a0=wredsum(a0); a1=wredsum(a1); a2=wredsum(a2); a3=wredsum(a3);
    a4=wredsum(a4); a5=wredsum(a5); a6=wredsum(a6); a7=wredsum(a7);
    int lane=t&63, wid=t>>6;
    if (lane==0){
      sm[wid*8+0]=a0; sm[wid*8+1]=a1; sm[wid*8+2]=a2; sm[wid*8+3]=a3;
      sm[wid*8+4]=a4; sm[wid*8+5]=a5; sm[wid*8+6]=a6; sm[wid*8+7]=a7;
    }
    __syncthreads();
    if (t<8){
      float s=sm[t]+sm[8+t]+sm[16+t]+sm[24+t];
      if (t<4) SKC[(t>>1)*256 + c0 + (t&1)] = s;
      else     SVC[((t-4)>>1)*256 + c0 + ((t-4)&1)] = s;
    }
    __syncthreads();
    if (g==0){
      float* wl = sm+64;
      if (t<64) wl[t] = noise[t];
      __syncthreads();
      for (int i=0;i<4;i++){
        float acc=0.f;
        if (t<64){
          for (int in_=0;in_<64;in_++) acc += wl[in_]*iw[(i*64+in_)*64+t];
          acc += ib[i*64+t];
        }
        __syncthreads();
        if (t<64) wl[t]=acc;
        __syncthreads();
      }
      if (t<64) WVEC[t]=wl[t];
      if (t==0) *SLOT = 0ull;
    }
    if (g==1){
      Yg[t] = emb[t] + pe_val(0,t);
      if (t==0) out[0]=0;
    }
  }
  gbar(ARR,REL,++ep);

  // ================= Prelude B: KAP / UT / CC / BETA tables =================
  {
    int c0 = 2*g;
    float p00 = bv[t]    *Wo[t*256+c0],        p01 = bv[t]    *Wo[t*256+c0+1];
    float p10 = bv[256+t]*Wo[65536+t*256+c0],  p11 = bv[256+t]*Wo[65536+t*256+c0+1];
    p00=wredsum(p00); p01=wredsum(p01); p10=wredsum(p10); p11=wredsum(p11);
    int lane=t&63, wid=t>>6;
    if (lane==0){ sm[wid*4+0]=p00; sm[wid*4+1]=p01; sm[wid*4+2]=p10; sm[wid*4+3]=p11; }
    __syncthreads();
    if (t<4){
      float s=sm[t]+sm[4+t]+sm[8+t]+sm[12+t];
      int i=t>>1, cl=t&1;
      CC[i*256+c0+cl] = s + bo[i*256+c0+cl];
    }
    if (t<32){
      int i=t>>4, h=(t>>1)&7, c=c0+(t&1);
      float s=0.f;
      for (int e2=0;e2<32;e2++) s += SVC[i*256+h*32+e2]*Wo[i*65536+(h*32+e2)*256+c];
      UT[(i*8+h)*256+c]=s;
    }
    if (t>=32 && t<64){
      int u=t-32, i=u>>4, h=(u>>1)&7, e=c0+(u&1);
      float s=0.f;
      for (int c2=0;c2<32;c2++) s += Wq[i*65536+e*256+h*32+c2]*SKC[i*256+h*32+c2];
      KAP[(i*8+h)*256+e]=s;
    }
    if (g==0 && t>=64 && t<80){
      int u=t-64, i=u>>3, h=u&7;
      float s=0.f;
      for (int c2=0;c2<32;c2++) s += bq[i*256+h*32+c2]*SKC[i*256+h*32+c2];
      BETA[i*8+h]=s;
    }
  }
  gbar(ARR,REL,++ep);

  // ================= decode loop =================
  for (int tok=1; tok<64; tok++){
    const int n = tok-1;

    // ---- Stage A: WG-per-row, both cross blocks (rank-1 collapsed) -> r1 ----
    if (g < tok){
      const int q = g;
      float* xrow = sm; float* rrow = sm+256; float* m8 = sm+512; float* redv = sm+528;
      if (q==n && tok>1){
        unsigned long long s = __hip_atomic_load(SLOT, __ATOMIC_RELAXED, __HIP_MEMORY_SCOPE_AGENT);
        int v = (int)(~(unsigned int)(s & 0xffffffffull));
        if (t==0) out[q]=v;
        float yv = emb[v*256+t] + pe_val(q,t);
        xrow[t]=yv; Yg[q*256+t]=yv;
      } else {
        xrow[t]=Yg[q*256+t];
      }
      __syncthreads();
      for (int blk=0; blk<2; blk++){
        const float* src = blk ? rrow : xrow;
        int h=t>>5, j=t&31;
        float part=0.f;
        for (int jj=j; jj<256; jj+=32) part += src[jj]*KAP[(blk*8+h)*256+jj];
        part = g32sum(part);
        float alpha = (part + BETA[blk*8+h]) * ISQ;
        float s1 = (j<tok)     ? alpha*WVEC[j]    : -3.4e38f;
        float s2 = (j+32<tok)  ? alpha*WVEC[j+32] : -3.4e38f;
        float mx = g32max(fmaxf(s1,s2));
        float e1 = expf(s1-mx), e2 = expf(s2-mx);
        float sn = e1*((j<tok)?WVEC[j]:0.f) + e2*((j+32<tok)?WVEC[j+32]:0.f);
        float sd = e1+e2;
        sn=g32sum(sn); sd=g32sum(sd);
        if (j==0) m8[h]=sn/sd;
        __syncthreads();
        float x_ = blk ? rrow[t] : xrow[t];
        float z = CC[blk*256+t] + x_;
#pragma unroll
        for (int h2=0;h2<8;h2++) z += m8[h2]*UT[(blk*8+h2)*256+t];
        float ssum=wredsum(z), ssq=wredsum(z*z);
        int lane=t&63, wid=t>>6;
        if (lane==0){ redv[wid]=ssum; redv[4+wid]=ssq; }
        __syncthreads();
        float ts=redv[0]+redv[1]+redv[2]+redv[3];
        float tq=redv[4]+redv[5]+redv[6]+redv[7];
        float mu=ts*(1.f/256.f);
        float var=tq*(1.f/256.f)-mu*mu;
        float rstd=1.f/sqrtf(var+1e-5f);
        float rv=(z-mu)*rstd*lng[blk*256+t]+lnb[blk*256+t];
        __syncthreads();
        rrow[t]=rv;
        __syncthreads();
      }
      R1[q*256+t]=rrow[t];
    }
    gbar(ARR,REL,++ep);

    // ---- Stage B: self0 Q/K/V projection, (rowgroup, head) mapping ----
    {
      if (g==0 && t==0) __hip_atomic_store(SLOT, 0ull, __ATOMIC_RELAXED, __HIP_MEMORY_SCOPE_AGENT);
      const int h=g&7, rg=g>>3;
      float* rows4 = sm; // [4][256]
#pragma unroll
      for (int jj=0;jj<4;jj++) rows4[jj*256+t] = R1[(rg+16*jj)*256+t];
      __syncthreads();
      int c=t&31, epp=t>>5;
      const int col=h*32+c;
      float aq[4]={0,0,0,0}, ak[4]={0,0,0,0}, av[4]={0,0,0,0};
#pragma unroll 8
      for (int e=epp*32; e<epp*32+32; e++){
        float wq_=Wq[e*256+col], wk_=Wk[e*256+col], wv_=Wv[e*256+col];
#pragma unroll
        for (int jj=0;jj<4;jj++){ float r=rows4[jj*256+e]; aq[jj]+=r*wq_; ak[jj]+=r*wk_; av[jj]+=r*wv_; }
      }
#pragma unroll
      for (int jj=0;jj<4;jj++){
        aq[jj]+=__shfl_xor(aq[jj],32,64);
        ak[jj]+=__shfl_xor(ak[jj],32,64);
        av[jj]+=__shfl_xor(av[jj],32,64);
      }
      float4* redq=(float4*)(sm+1056); float4* redk=(float4*)(sm+1568); float4* redv4=(float4*)(sm+2080);
      int lane=t&63, wid=t>>6;
      if (lane<32){
        redq[wid*32+lane]=make_float4(aq[0],aq[1],aq[2],aq[3]);
        redk[wid*32+lane]=make_float4(ak[0],ak[1],ak[2],ak[3]);
        redv4[wid*32+lane]=make_float4(av[0],av[1],av[2],av[3]);
      }
      __syncthreads();
      if (t<32){
        float4 A=redq[t],B4=redq[32+t],C4=redq[64+t],D4=redq[96+t];
        float sq[4]={A.x+B4.x+C4.x+D4.x, A.y+B4.y+C4.y+D4.y, A.z+B4.z+C4.z+D4.z, A.w+B4.w+C4.w+D4.w};
        A=redk[t];B4=redk[32+t];C4=redk[64+t];D4=redk[96+t];
        float sk[4]={A.x+B4.x+C4.x+D4.x, A.y+B4.y+C4.y+D4.y, A.z+B4.z+C4.z+D4.z, A.w+B4.w+C4.w+D4.w};
        A=redv4[t];B4=redv4[32+t];C4=redv4[64+t];D4=redv4[96+t];
        float sv[4]={A.x+B4.x+C4.x+D4.x, A.y+B4.y+C4.y+D4.y, A.z+B4.z+C4.z+D4.z, A.w+B4.w+C4.w+D4.w};
        int cc=h*32+t;
        float bq_=bq[cc], bk_=bk[cc], bv_=bv[cc];
#pragma unroll
        for (int jj=0;jj<4;jj++){
          int q_=rg+16*jj;
          if (q_<tok){
            QB[q_*256+cc]=sq[jj]+bq_;
            KB[q_*256+cc]=sk[jj]+bk_;
            VB[q_*256+cc]=sv[jj]+bv_;
          }
        }
      }
    }
    gbar(ARR,REL,++ep);

    // ---- Stage C: self0 attention + per-head partial O-proj -> Z2P ----
    {
      const int h=g&7, rg=g>>3;
      float* Ks=sm; float* Vs=sm+2112; float* qrow=sm+4224; float* arow=sm+4352; float* o2s=sm+4608;
      int k=t>>2, f0=(t&3)*8;
      if (k<tok){
#pragma unroll
        for (int i2=0;i2<8;i2++){
          Ks[k*33+f0+i2]=KB[k*256+h*32+f0+i2];
          Vs[k*33+f0+i2]=VB[k*256+h*32+f0+i2];
        }
      }
      if (t<128){ int jj=t>>5, c=t&31; int q_=rg+16*jj; if (q_<tok) qrow[jj*32+c]=QB[q_*256+h*32+c]; }
      __syncthreads();
      int w=t>>6, lane=t&63; int q_=rg+16*w; bool ok=q_<tok;
      float sc=-3.4e38f;
      if (ok && lane<tok){
        sc=0.f;
#pragma unroll
        for (int c2=0;c2<32;c2++) sc+=qrow[w*32+c2]*Ks[lane*33+c2];
        sc*=ISQ;
      }
      float mx=wredmax(sc);
      float ex=(ok&&lane<tok)? expf(sc-mx):0.f;
      float sd=wredsum(ex);
      arow[w*64+lane]= ok ? ex/sd : 0.f;
      __syncthreads();
      int j=lane&31, half=lane>>5;
      float oa=0.f;
      if (ok){ for (int k2=half;k2<tok;k2+=2) oa+=arow[w*64+k2]*Vs[k2*33+j]; }
      oa += __shfl_xor(oa,32,64);
      if (lane<32) o2s[w*32+j]=oa;
      __syncthreads();
      float acc[4]={0,0,0,0};
#pragma unroll 8
      for (int j2=0;j2<32;j2++){
        float wv_=Wo[(h*32+j2)*256+t];
#pragma unroll
        for (int jj=0;jj<4;jj++) acc[jj]+=o2s[jj*32+j2]*wv_;
      }
#pragma unroll
      for (int jj=0;jj<4;jj++){ int q2=rg+16*jj; if (q2<tok) Z2P[(h*64+q2)*256+t]=acc[jj]; }
    }
    gbar(ARR,REL,++ep);

    // ---- Stage E: z2 assemble + LN -> r2 ; self1 K/V proj (+Q for row n) ----
    {
      const int h=g&7, rg=g>>3;
      float* rows4=sm; float* mus=sm+1024;
#pragma unroll
      for (int jj=0;jj<4;jj++){
        int q_=rg+16*jj;
        float z = bo[t] + R1[q_*256+t];
#pragma unroll
        for (int h2=0;h2<8;h2++) z += Z2P[(h2*64+q_)*256+t];
        rows4[jj*256+t]=z;
      }
      __syncthreads();
      {
        int w=t>>6, lane=t&63;
        float v0=rows4[w*256+lane], v1=rows4[w*256+64+lane], v2=rows4[w*256+128+lane], v3=rows4[w*256+192+lane];
        float s=v0+v1+v2+v3, sq2=v0*v0+v1*v1+v2*v2+v3*v3;
        s=wredsum(s); sq2=wredsum(sq2);
        if (lane==0){
          float mu=s*(1.f/256.f);
          float var=sq2*(1.f/256.f)-mu*mu;
          mus[w*2]=mu; mus[w*2+1]=1.f/sqrtf(var+1e-5f);
        }
      }
      __syncthreads();
#pragma unroll
      for (int jj=0;jj<4;jj++){
        float mu=mus[jj*2], rstd=mus[jj*2+1];
        float val=(rows4[jj*256+t]-mu)*rstd*lng[t]+lnb[t];   // self0 uses ln index 0
        rows4[jj*256+t]=val;
        int q_=rg+16*jj;
        if (h==0 && q_<tok) R2[q_*256+t]=val;
      }
      __syncthreads();
      int c=t&31, epp=t>>5;
      const int col=h*32+c;
      float aq[4]={0,0,0,0}, ak[4]={0,0,0,0}, av[4]={0,0,0,0};
#pragma unroll 8
      for (int e=epp*32; e<epp*32+32; e++){
        float wq_=Wq[65536+e*256+col], wk_=Wk[65536+e*256+col], wv_=Wv[65536+e*256+col];
#pragma unroll
        for (int jj=0;jj<4;jj++){ float r=rows4[jj*256+e]; aq[jj]+=r*wq_; ak[jj]+=r*wk_; av[jj]+=r*wv_; }
      }
#pragma unroll
      for (int jj=0;jj<4;jj++){
        aq[jj]+=__shfl_xor(aq[jj],32,64);
        ak[jj]+=__shfl_xor(ak[jj],32,64);
        av[jj]+=__shfl_xor(av[jj],32,64);
      }
      float4* redq=(float4*)(sm+1056); float4* redk=(float4*)(sm+1568); float4* redv4=(float4*)(sm+2080);
      int lane=t&63, wid=t>>6;
      if (lane<32){
        redq[wid*32+lane]=make_float4(aq[0],aq[1],aq[2],aq[3]);
        redk[wid*32+lane]=make_float4(ak[0],ak[1],ak[2],ak[3]);
        redv4[wid*32+lane]=make_float4(av[0],av[1],av[2],av[3]);
      }
      __syncthreads();
      if (t<32){
        float4 A=redq[t],B4=redq[32+t],C4=redq[64+t],D4=redq[96+t];
        float sq[4]={A.x+B4.x+C4.x+D4.x, A.y+B4.y+C4.y+D4.y, A.z+B4.z+C4.z+D4.z, A.w+B4.w+C4.w+D4.w};
        A=redk[t];B4=redk[32+t];C4=redk[64+t];D4=redk[96+t];
        float sk[4]={A.x+B4.x+C4.x+D4.x, A.y+B4.y+C4.y+D4.y, A.z+B4.z+C4.z+D4.z, A.w+B4.w+C4.w+D4.w};
        A=redv4[t];B4=redv4[32+t];C4=redv4[64+t];D4=redv4[96+t];
        float sv[4]={A.x+B4.x+C4.x+D4.x, A.y+B4.y+C4.y+D4.y, A.z+B4.z+C4.z+D4.z, A.w+B4.w+C4.w+D4.w};
        int cc=h*32+t;
#pragma unroll
        for (int jj=0;jj<4;jj++){
          int q_=rg+16*jj;
          if (q_<tok){
            KB[q_*256+cc]=sk[jj]+bk[256+cc];
            VB[q_*256+cc]=sv[jj]+bv[256+cc];
            if (q_==n) QB[q_*256+cc]=sq[jj]+bq[256+cc];
          }
        }
      }
    }
    gbar(ARR,REL,++ep);

    // ---- Stage F: self1 attention for row n only + per-head partial O-proj -> Z3P ----
    {
      const int h=g&7, rg=g>>3;
      if (rg == (n&15)){
        float* Ks=sm; float* Vs=sm+2112; float* qn=sm+4224; float* arow=sm+4352; float* o3s=sm+4608;
        int k=t>>2, f0=(t&3)*8;
        if (k<tok){
#pragma unroll
          for (int i2=0;i2<8;i2++){
            Ks[k*33+f0+i2]=KB[k*256+h*32+f0+i2];
            Vs[k*33+f0+i2]=VB[k*256+h*32+f0+i2];
          }
        }
        if (t<32) qn[t]=QB[n*256+h*32+t];
        __syncthreads();
        int lane=t&63, w=t>>6;
        if (w==0){
          float sc=-3.4e38f;
          if (lane<tok){
            sc=0.f;
#pragma unroll
            for (int c2=0;c2<32;c2++) sc+=qn[c2]*Ks[lane*33+c2];
            sc*=ISQ;
          }
          float mx=wredmax(sc);
          float ex=(lane<tok)? expf(sc-mx):0.f;
          float sd=wredsum(ex);
          arow[lane]=ex/sd;
        }
        __syncthreads();
        if (w==0){
          int j=lane&31, half=lane>>5;
          float oa=0.f;
          for (int k2=half;k2<tok;k2+=2) oa+=arow[k2]*Vs[k2*33+j];
          oa+=__shfl_xor(oa,32,64);
          if (lane<32) o3s[j]=oa;
        }
        __syncthreads();
        float acc=0.f;
#pragma unroll 8
        for (int j2=0;j2<32;j2++) acc+=o3s[j2]*Wo[65536+(h*32+j2)*256+t];
        Z3P[h*256+t]=acc;
      }
    }
    gbar(ARR,REL,++ep);

    // ---- Stage H: z3 assemble + LN + logits (v-sliced) + packed argmax ----
    {
      float* outn=sm; float* redv=sm+256;
      float z = bo[256+t] + R2[n*256+t];
#pragma unroll
      for (int h2=0;h2<8;h2++) z += Z3P[h2*256+t];
      float s=wredsum(z), sq2=wredsum(z*z);
      int lane=t&63, wid=t>>6;
      if (lane==0){ redv[wid]=s; redv[4+wid]=sq2; }
      __syncthreads();
      float ts=redv[0]+redv[1]+redv[2]+redv[3];
      float tq=redv[4]+redv[5]+redv[6]+redv[7];
      float mu=ts*(1.f/256.f);
      float var=tq*(1.f/256.f)-mu*mu;
      float rstd=1.f/sqrtf(var+1e-5f);
      outn[t]=(z-mu)*rstd*lng[256+t]+lnb[256+t];
      __syncthreads();
      unsigned long long key=0ull;
      if (t<125){
        int v=g*125+t;
        float acc=sb[v];
#pragma unroll 8
        for (int e=0;e<256;e++) acc += outn[e]*sw[e*16000+v];
        unsigned int fb=__float_as_uint(acc);
        fb = (fb&0x80000000u)? ~fb : (fb|0x80000000u);
        key=(((unsigned long long)fb)<<32) | (unsigned long long)(~(unsigned int)v);
      }
#pragma unroll
      for (int m=32;m;m>>=1){
        unsigned long long o=shflx64(key,m);
        key = (o>key)? o : key;
      }
      if (lane==0) redU[wid]=key;
      __syncthreads();
      if (t==0){
        unsigned long long kk=redU[0];
        if (redU[1]>kk) kk=redU[1];
        if (redU[2]>kk) kk=redU[2];
        if (redU[3]>kk) kk=redU[3];
        atomicMax(SLOT, kk);
      }
    }
    gbar(ARR,REL,++ep);
  }

  // epilogue: final winner
  if (g==0 && t==0){
    unsigned long long s=__hip_atomic_load(SLOT,__ATOMIC_RELAXED,__HIP_MEMORY_SCOPE_AGENT);
    out[63]=(int)(~(unsigned int)(s&0xffffffffull));
  }
}

extern "C" void kernel_launch(void* const* d_in, const int* in_sizes, int n_in,
                              void* d_out, int out_size, void* d_ws, size_t ws_size,
                              hipStream_t stream)
{
  (void)in_sizes; (void)n_in; (void)out_size; (void)ws_size;
  hipLaunchKernelGGL(gen18124_kernel, dim3(NWG), dim3(NT), 0, stream,
    (const float*)d_in[0],  (const float*)d_in[1],  (const float*)d_in[2],
    (const float*)d_in[3],  (const float*)d_in[4],  (const float*)d_in[5],
    (const float*)d_in[6],  (const float*)d_in[7],  (const float*)d_in[8],
    (const float*)d_in[9],  (const float*)d_in[10], (const float*)d_in[11],
    (const float*)d_in[12], (const float*)d_in[13], (const float*)d_in[14],
    (const float*)d_in[15], (int*)d_out, (float*)d_ws);
}

// Round 2
// 4655.883 us; speedup vs baseline: 3.3035x; 3.3035x over previous
//
#include <hip/hip_runtime.h>
#include <stdint.h>

// Persistent-kernel autoregressive decode for Generator_18124761989654.
// R1 -> R2 changes:
//  (1) gbar spins with RELAXED agent loads (one release fence on arrive, one
//      acquire fence on depart) -- kills the per-poll buffer_inv L2-invalidation
//      storm that made every barrier ~35us and forced soft_W refetch each step.
//  (2) soft_W slice (125 cols x 256 rows = 128KB) pinned in dynamic LDS per WG,
//      loaded once in prelude; logits GEMV reads LDS only, e-range split across
//      thread halves.

#define NWG 128
#define NT 256

__device__ __forceinline__ float wredsum(float v){
#pragma unroll
  for (int m=32;m;m>>=1) v += __shfl_xor(v,m,64);
  return v;
}
__device__ __forceinline__ float wredmax(float v){
#pragma unroll
  for (int m=32;m;m>>=1) v = fmaxf(v,__shfl_xor(v,m,64));
  return v;
}
__device__ __forceinline__ float g32sum(float v){
#pragma unroll
  for (int m=16;m;m>>=1) v += __shfl_xor(v,m,64);
  return v;
}
__device__ __forceinline__ float g32max(float v){
#pragma unroll
  for (int m=16;m;m>>=1) v = fmaxf(v,__shfl_xor(v,m,64));
  return v;
}
__device__ __forceinline__ unsigned long long shflx64(unsigned long long v,int m){
  unsigned int lo=(unsigned int)(v&0xffffffffull), hi=(unsigned int)(v>>32);
  lo=__shfl_xor(lo,m,64); hi=__shfl_xor(hi,m,64);
  return (((unsigned long long)hi)<<32)|(unsigned long long)lo;
}

__device__ __forceinline__ float pe_val(int l, int e){
  int j = e >> 1;
  float dv = expf((float)(2*j) * (-0.035977892078031970f));
  float arg = (float)l * dv;
  return (e & 1) ? cosf(arg) : sinf(arg);
}

// epoch grid barrier; RELAXED spins + single release/acquire fences.
// equality test => safe with 0xAA-poisoned flags (negative int)
__device__ __forceinline__ void gbar(int* arr, int* rel, int ep){
  __syncthreads();
  if (threadIdx.x==0){
    __builtin_amdgcn_fence(__ATOMIC_RELEASE, "agent");   // one wbl2: publish this WG's stores
    __hip_atomic_store(arr + blockIdx.x*16, ep, __ATOMIC_RELAXED, __HIP_MEMORY_SCOPE_AGENT);
  }
  if (blockIdx.x==0){
    if (threadIdx.x < NWG){
      while (__hip_atomic_load(arr + threadIdx.x*16, __ATOMIC_RELAXED, __HIP_MEMORY_SCOPE_AGENT) != ep)
        __builtin_amdgcn_s_sleep(1);
    }
    __syncthreads();
    if (threadIdx.x==0)
      __hip_atomic_store(rel, ep, __ATOMIC_RELAXED, __HIP_MEMORY_SCOPE_AGENT);
  }
  if (threadIdx.x==0){
    while (__hip_atomic_load(rel, __ATOMIC_RELAXED, __HIP_MEMORY_SCOPE_AGENT) != ep)
      __builtin_amdgcn_s_sleep(1);
    __builtin_amdgcn_fence(__ATOMIC_ACQUIRE, "agent");   // one buffer_inv: see others' stores
  }
  __syncthreads();
}

extern "C" __global__ __launch_bounds__(256, 2)
void gen18124_kernel(const float* __restrict__ noise,
                     const float* __restrict__ iw, const float* __restrict__ ib,
                     const float* __restrict__ Wq, const float* __restrict__ bq,
                     const float* __restrict__ Wk, const float* __restrict__ bk,
                     const float* __restrict__ Wv, const float* __restrict__ bv,
                     const float* __restrict__ Wo, const float* __restrict__ bo,
                     const float* __restrict__ lng, const float* __restrict__ lnb,
                     const float* __restrict__ emb, const float* __restrict__ sw,
                     const float* __restrict__ sb,
                     int* __restrict__ out, float* __restrict__ ws)
{
  const float ISQ = 0.17677669529663687f; // 1/sqrt(32)
  __shared__ float sm[5376];
  __shared__ unsigned long long redU[4];
  extern __shared__ float swl[];          // [256][128] soft_W slice, 128KB

  // ---- workspace layout (floats) ----
  float* WVEC = ws;            // 64
  float* SKC  = ws+64;         // [2][256] colsum(Wk)
  float* SVC  = ws+576;        // [2][256] colsum(Wv)
  float* KAP  = ws+1088;       // [2][8][256]
  float* UT   = ws+5184;       // [2][8][256]
  float* CC   = ws+9280;       // [2][256]
  float* BETA = ws+9792;       // [2][8]
  unsigned long long* SLOT = (unsigned long long*)(ws+9808);
  int* ARR = (int*)(ws+9824);  // 128 * stride16 ints
  int* REL = (int*)(ws+11872);
  float* Yg  = ws+11876;       // [64][256]
  float* R1  = ws+28260;       // [64][256]
  float* QB  = ws+44644;       // [64][256]
  float* KB  = ws+61028;       // [64][256]
  float* VB  = ws+77412;       // [64][256]
  float* R2  = ws+93796;       // [64][256]
  float* Z2P = ws+110180;      // [8][64][256]
  float* Z3P = ws+241252;      // [8][256]

  const int g = blockIdx.x, t = threadIdx.x;
  int ep = 0;

  // ---- soft_W slice -> LDS (WG-private, no barrier needed) ----
  {
    const int base = g*125;
#pragma unroll 8
    for (int i=t; i<256*128; i+=NT){
      int e=i>>7, c=i&127;
      float val = 0.f;
      if (c<125) val = sw[e*16000 + base + c];
      swl[i]=val;
    }
  }

  // ================= Prelude A: colsums, wvec, Y0, slot/out init =================
  {
    int c0 = 2*g;
    float a0=Wk[t*256+c0],       a1=Wk[t*256+c0+1];
    float a2=Wk[65536+t*256+c0], a3=Wk[65536+t*256+c0+1];
    float a4=Wv[t*256+c0],       a5=Wv[t*256+c0+1];
    float a6=Wv[65536+t*256+c0], a7=Wv[65536+t*256+c0+1];
    a0=wredsum(a0); a1=wredsum(a1); a2=wredsum(a2); a3=wredsum(a3);
    a4=wredsum(a4); a5=wredsum(a5); a6=wredsum(a6); a7=wredsum(a7);
    int lane=t&63, wid=t>>6;
    if (lane==0){
      sm[wid*8+0]=a0; sm[wid*8+1]=a1; sm[wid*8+2]=a2; sm[wid*8+3]=a3;
      sm[wid*8+4]=a4; sm[wid*8+5]=a5; sm[wid*8+6]=a6; sm[wid*8+7]=a7;
    }
    __syncthreads();
    if (t<8){
      float s=sm[t]+sm[8+t]+sm[16+t]+sm[24+t];
      if (t<4) SKC[(t>>1)*256 + c0 + (t&1)] = s;
      else     SVC[((t-4)>>1)*256 + c0 + ((t-4)&1)] = s;
    }
    __syncthreads();
    if (g==0){
      float* wl = sm+64;
      if (t<64) wl[t] = noise[t];
      __syncthreads();
      for (int i=0;i<4;i++){
        float acc=0.f;
        if (t<64){
          for (int in_=0;in_<64;in_++) acc += wl[in_]*iw[(i*64+in_)*64+t];
          acc += ib[i*64+t];
        }
        __syncthreads();
        if (t<64) wl[t]=acc;
        __syncthreads();
      }
      if (t<64) WVEC[t]=wl[t];
      if (t==0) *SLOT = 0ull;
    }
    if (g==1){
      Yg[t] = emb[t] + pe_val(0,t);
      if (t==0) out[0]=0;
    }
  }
  gbar(ARR,REL,++ep);

  // ================= Prelude B: KAP / UT / CC / BETA tables =================
  {
    int c0 = 2*g;
    float p00 = bv[t]    *Wo[t*256+c0],        p01 = bv[t]    *Wo[t*256+c0+1];
    float p10 = bv[256+t]*Wo[65536+t*256+c0],  p11 = bv[256+t]*Wo[65536+t*256+c0+1];
    p00=wredsum(p00); p01=wredsum(p01); p10=wredsum(p10); p11=wredsum(p11);
    int lane=t&63, wid=t>>6;
    if (lane==0){ sm[wid*4+0]=p00; sm[wid*4+1]=p01; sm[wid*4+2]=p10; sm[wid*4+3]=p11; }
    __syncthreads();
    if (t<4){
      float s=sm[t]+sm[4+t]+sm[8+t]+sm[12+t];
      int i=t>>1, cl=t&1;
      CC[i*256+c0+cl] = s + bo[i*256+c0+cl];
    }
    if (t<32){
      int i=t>>4, h=(t>>1)&7, c=c0+(t&1);
      float s=0.f;
      for (int e2=0;e2<32;e2++) s += SVC[i*256+h*32+e2]*Wo[i*65536+(h*32+e2)*256+c];
      UT[(i*8+h)*256+c]=s;
    }
    if (t>=32 && t<64){
      int u=t-32, i=u>>4, h=(u>>1)&7, e=c0+(u&1);
      float s=0.f;
      for (int c2=0;c2<32;c2++) s += Wq[i*65536+e*256+h*32+c2]*SKC[i*256+h*32+c2];
      KAP[(i*8+h)*256+e]=s;
    }
    if (g==0 && t>=64 && t<80){
      int u=t-64, i=u>>3, h=u&7;
      float s=0.f;
      for (int c2=0;c2<32;c2++) s += bq[i*256+h*32+c2]*SKC[i*256+h*32+c2];
      BETA[i*8+h]=s;
    }
  }
  gbar(ARR,REL,++ep);

  // ================= decode loop =================
  for (int tok=1; tok<64; tok++){
    const int n = tok-1;

    // ---- Stage A: WG-per-row, both cross blocks (rank-1 collapsed) -> r1 ----
    if (g < tok){
      const int q = g;
      float* xrow = sm; float* rrow = sm+256; float* m8 = sm+512; float* redv = sm+528;
      if (q==n && tok>1){
        unsigned long long s = __hip_atomic_load(SLOT, __ATOMIC_RELAXED, __HIP_MEMORY_SCOPE_AGENT);
        int v = (int)(~(unsigned int)(s & 0xffffffffull));
        if (t==0) out[q]=v;
        float yv = emb[v*256+t] + pe_val(q,t);
        xrow[t]=yv; Yg[q*256+t]=yv;
      } else {
        xrow[t]=Yg[q*256+t];
      }
      __syncthreads();
      for (int blk=0; blk<2; blk++){
        const float* src = blk ? rrow : xrow;
        int h=t>>5, j=t&31;
        float part=0.f;
        for (int jj=j; jj<256; jj+=32) part += src[jj]*KAP[(blk*8+h)*256+jj];
        part = g32sum(part);
        float alpha = (part + BETA[blk*8+h]) * ISQ;
        float s1 = (j<tok)     ? alpha*WVEC[j]    : -3.4e38f;
        float s2 = (j+32<tok)  ? alpha*WVEC[j+32] : -3.4e38f;
        float mx = g32max(fmaxf(s1,s2));
        float e1 = expf(s1-mx), e2 = expf(s2-mx);
        float sn = e1*((j<tok)?WVEC[j]:0.f) + e2*((j+32<tok)?WVEC[j+32]:0.f);
        float sd = e1+e2;
        sn=g32sum(sn); sd=g32sum(sd);
        if (j==0) m8[h]=sn/sd;
        __syncthreads();
        float x_ = blk ? rrow[t] : xrow[t];
        float z = CC[blk*256+t] + x_;
#pragma unroll
        for (int h2=0;h2<8;h2++) z += m8[h2]*UT[(blk*8+h2)*256+t];
        float ssum=wredsum(z), ssq=wredsum(z*z);
        int lane=t&63, wid=t>>6;
        if (lane==0){ redv[wid]=ssum; redv[4+wid]=ssq; }
        __syncthreads();
        float ts=redv[0]+redv[1]+redv[2]+redv[3];
        float tq=redv[4]+redv[5]+redv[6]+redv[7];
        float mu=ts*(1.f/256.f);
        float var=tq*(1.f/256.f)-mu*mu;
        float rstd=1.f/sqrtf(var+1e-5f);
        float rv=(z-mu)*rstd*lng[blk*256+t]+lnb[blk*256+t];
        __syncthreads();
        rrow[t]=rv;
        __syncthreads();
      }
      R1[q*256+t]=rrow[t];
    }
    gbar(ARR,REL,++ep);

    // ---- Stage B: self0 Q/K/V projection, (rowgroup, head) mapping ----
    {
      if (g==0 && t==0) __hip_atomic_store(SLOT, 0ull, __ATOMIC_RELAXED, __HIP_MEMORY_SCOPE_AGENT);
      const int h=g&7, rg=g>>3;
      float* rows4 = sm; // [4][256]
#pragma unroll
      for (int jj=0;jj<4;jj++) rows4[jj*256+t] = R1[(rg+16*jj)*256+t];
      __syncthreads();
      int c=t&31, epp=t>>5;
      const int col=h*32+c;
      float aq[4]={0,0,0,0}, ak[4]={0,0,0,0}, av[4]={0,0,0,0};
#pragma unroll 8
      for (int e=epp*32; e<epp*32+32; e++){
        float wq_=Wq[e*256+col], wk_=Wk[e*256+col], wv_=Wv[e*256+col];
#pragma unroll
        for (int jj=0;jj<4;jj++){ float r=rows4[jj*256+e]; aq[jj]+=r*wq_; ak[jj]+=r*wk_; av[jj]+=r*wv_; }
      }
#pragma unroll
      for (int jj=0;jj<4;jj++){
        aq[jj]+=__shfl_xor(aq[jj],32,64);
        ak[jj]+=__shfl_xor(ak[jj],32,64);
        av[jj]+=__shfl_xor(av[jj],32,64);
      }
      float4* redq=(float4*)(sm+1056); float4* redk=(float4*)(sm+1568); float4* redv4=(float4*)(sm+2080);
      int lane=t&63, wid=t>>6;
      if (lane<32){
        redq[wid*32+lane]=make_float4(aq[0],aq[1],aq[2],aq[3]);
        redk[wid*32+lane]=make_float4(ak[0],ak[1],ak[2],ak[3]);
        redv4[wid*32+lane]=make_float4(av[0],av[1],av[2],av[3]);
      }
      __syncthreads();
      if (t<32){
        float4 A=redq[t],B4=redq[32+t],C4=redq[64+t],D4=redq[96+t];
        float sq[4]={A.x+B4.x+C4.x+D4.x, A.y+B4.y+C4.y+D4.y, A.z+B4.z+C4.z+D4.z, A.w+B4.w+C4.w+D4.w};
        A=redk[t];B4=redk[32+t];C4=redk[64+t];D4=redk[96+t];
        float sk[4]={A.x+B4.x+C4.x+D4.x, A.y+B4.y+C4.y+D4.y, A.z+B4.z+C4.z+D4.z, A.w+B4.w+C4.w+D4.w};
        A=redv4[t];B4=redv4[32+t];C4=redv4[64+t];D4=redv4[96+t];
        float sv[4]={A.x+B4.x+C4.x+D4.x, A.y+B4.y+C4.y+D4.y, A.z+B4.z+C4.z+D4.z, A.w+B4.w+C4.w+D4.w};
        int cc=h*32+t;
        float bq_=bq[cc], bk_=bk[cc], bv_=bv[cc];
#pragma unroll
        for (int jj=0;jj<4;jj++){
          int q_=rg+16*jj;
          if (q_<tok){
            QB[q_*256+cc]=sq[jj]+bq_;
            KB[q_*256+cc]=sk[jj]+bk_;
            VB[q_*256+cc]=sv[jj]+bv_;
          }
        }
      }
    }
    gbar(ARR,REL,++ep);

    // ---- Stage C: self0 attention + per-head partial O-proj -> Z2P ----
    {
      const int h=g&7, rg=g>>3;
      float* Ks=sm; float* Vs=sm+2112; float* qrow=sm+4224; float* arow=sm+4352; float* o2s=sm+4608;
      int k=t>>2, f0=(t&3)*8;
      if (k<tok){
#pragma unroll
        for (int i2=0;i2<8;i2++){
          Ks[k*33+f0+i2]=KB[k*256+h*32+f0+i2];
          Vs[k*33+f0+i2]=VB[k*256+h*32+f0+i2];
        }
      }
      if (t<128){ int jj=t>>5, c=t&31; int q_=rg+16*jj; if (q_<tok) qrow[jj*32+c]=QB[q_*256+h*32+c]; }
      __syncthreads();
      int w=t>>6, lane=t&63; int q_=rg+16*w; bool ok=q_<tok;
      float sc=-3.4e38f;
      if (ok && lane<tok){
        sc=0.f;
#pragma unroll
        for (int c2=0;c2<32;c2++) sc+=qrow[w*32+c2]*Ks[lane*33+c2];
        sc*=ISQ;
      }
      float mx=wredmax(sc);
      float ex=(ok&&lane<tok)? expf(sc-mx):0.f;
      float sd=wredsum(ex);
      arow[w*64+lane]= ok ? ex/sd : 0.f;
      __syncthreads();
      int j=lane&31, half=lane>>5;
      float oa=0.f;
      if (ok){ for (int k2=half;k2<tok;k2+=2) oa+=arow[w*64+k2]*Vs[k2*33+j]; }
      oa += __shfl_xor(oa,32,64);
      if (lane<32) o2s[w*32+j]=oa;
      __syncthreads();
      float acc[4]={0,0,0,0};
#pragma unroll 8
      for (int j2=0;j2<32;j2++){
        float wv_=Wo[(h*32+j2)*256+t];
#pragma unroll
        for (int jj=0;jj<4;jj++) acc[jj]+=o2s[jj*32+j2]*wv_;
      }
#pragma unroll
      for (int jj=0;jj<4;jj++){ int q2=rg+16*jj; if (q2<tok) Z2P[(h*64+q2)*256+t]=acc[jj]; }
    }
    gbar(ARR,REL,++ep);

    // ---- Stage E: z2 assemble + LN -> r2 ; self1 K/V proj (+Q for row n) ----
    {
      const int h=g&7, rg=g>>3;
      float* rows4=sm; float* mus=sm+1024;
#pragma unroll
      for (int jj=0;jj<4;jj++){
        int q_=rg+16*jj;
        float z = bo[t] + R1[q_*256+t];
#pragma unroll
        for (int h2=0;h2<8;h2++) z += Z2P[(h2*64+q_)*256+t];
        rows4[jj*256+t]=z;
      }
      __syncthreads();
      {
        int w=t>>6, lane=t&63;
        float v0=rows4[w*256+lane], v1=rows4[w*256+64+lane], v2=rows4[w*256+128+lane], v3=rows4[w*256+192+lane];
        float s=v0+v1+v2+v3, sq2=v0*v0+v1*v1+v2*v2+v3*v3;
        s=wredsum(s); sq2=wredsum(sq2);
        if (lane==0){
          float mu=s*(1.f/256.f);
          float var=sq2*(1.f/256.f)-mu*mu;
          mus[w*2]=mu; mus[w*2+1]=1.f/sqrtf(var+1e-5f);
        }
      }
      __syncthreads();
#pragma unroll
      for (int jj=0;jj<4;jj++){
        float mu=mus[jj*2], rstd=mus[jj*2+1];
        float val=(rows4[jj*256+t]-mu)*rstd*lng[t]+lnb[t];
        rows4[jj*256+t]=val;
        int q_=rg+16*jj;
        if (h==0 && q_<tok) R2[q_*256+t]=val;
      }
      __syncthreads();
      int c=t&31, epp=t>>5;
      const int col=h*32+c;
      float aq[4]={0,0,0,0}, ak[4]={0,0,0,0}, av[4]={0,0,0,0};
#pragma unroll 8
      for (int e=epp*32; e<epp*32+32; e++){
        float wq_=Wq[65536+e*256+col], wk_=Wk[65536+e*256+col], wv_=Wv[65536+e*256+col];
#pragma unroll
        for (int jj=0;jj<4;jj++){ float r=rows4[jj*256+e]; aq[jj]+=r*wq_; ak[jj]+=r*wk_; av[jj]+=r*wv_; }
      }
#pragma unroll
      for (int jj=0;jj<4;jj++){
        aq[jj]+=__shfl_xor(aq[jj],32,64);
        ak[jj]+=__shfl_xor(ak[jj],32,64);
        av[jj]+=__shfl_xor(av[jj],32,64);
      }
      float4* redq=(float4*)(sm+1056); float4* redk=(float4*)(sm+1568); float4* redv4=(float4*)(sm+2080);
      int lane=t&63, wid=t>>6;
      if (lane<32){
        redq[wid*32+lane]=make_float4(aq[0],aq[1],aq[2],aq[3]);
        redk[wid*32+lane]=make_float4(ak[0],ak[1],ak[2],ak[3]);
        redv4[wid*32+lane]=make_float4(av[0],av[1],av[2],av[3]);
      }
      __syncthreads();
      if (t<32){
        float4 A=redq[t],B4=redq[32+t],C4=redq[64+t],D4=redq[96+t];
        float sq[4]={A.x+B4.x+C4.x+D4.x, A.y+B4.y+C4.y+D4.y, A.z+B4.z+C4.z+D4.z, A.w+B4.w+C4.w+D4.w};
        A=redk[t];B4=redk[32+t];C4=redk[64+t];D4=redk[96+t];
        float sk[4]={A.x+B4.x+C4.x+D4.x, A.y+B4.y+C4.y+D4.y, A.z+B4.z+C4.z+D4.z, A.w+B4.w+C4.w+D4.w};
        A=redv4[t];B4=redv4[32+t];C4=redv4[64+t];D4=redv4[96+t];
        float sv[4]={A.x+B4.x+C4.x+D4.x, A.y+B4.y+C4.y+D4.y, A.z+B4.z+C4.z+D4.z, A.w+B4.w+C4.w+D4.w};
        int cc=h*32+t;
#pragma unroll
        for (int jj=0;jj<4;jj++){
          int q_=rg+16*jj;
          if (q_<tok){
            KB[q_*256+cc]=sk[jj]+bk[256+cc];
            VB[q_*256+cc]=sv[jj]+bv[256+cc];
            if (q_==n) QB[q_*256+cc]=sq[jj]+bq[256+cc];
          }
        }
      }
    }
    gbar(ARR,REL,++ep);

    // ---- Stage F: self1 attention for row n only + per-head partial O-proj -> Z3P ----
    {
      const int h=g&7, rg=g>>3;
      if (rg == (n&15)){
        float* Ks=sm; float* Vs=sm+2112; float* qn=sm+4224; float* arow=sm+4352; float* o3s=sm+4608;
        int k=t>>2, f0=(t&3)*8;
        if (k<tok){
#pragma unroll
          for (int i2=0;i2<8;i2++){
            Ks[k*33+f0+i2]=KB[k*256+h*32+f0+i2];
            Vs[k*33+f0+i2]=VB[k*256+h*32+f0+i2];
          }
        }
        if (t<32) qn[t]=QB[n*256+h*32+t];
        __syncthreads();
        int lane=t&63, w=t>>6;
        if (w==0){
          float sc=-3.4e38f;
          if (lane<tok){
            sc=0.f;
#pragma unroll
            for (int c2=0;c2<32;c2++) sc+=qn[c2]*Ks[lane*33+c2];
            sc*=ISQ;
          }
          float mx=wredmax(sc);
          float ex=(lane<tok)? expf(sc-mx):0.f;
          float sd=wredsum(ex);
          arow[lane]=ex/sd;
        }
        __syncthreads();
        if (w==0){
          int j=lane&31, half=lane>>5;
          float oa=0.f;
          for (int k2=half;k2<tok;k2+=2) oa+=arow[k2]*Vs[k2*33+j];
          oa+=__shfl_xor(oa,32,64);
          if (lane<32) o3s[j]=oa;
        }
        __syncthreads();
        float acc=0.f;
#pragma unroll 8
        for (int j2=0;j2<32;j2++) acc+=o3s[j2]*Wo[65536+(h*32+j2)*256+t];
        Z3P[h*256+t]=acc;
      }
    }
    gbar(ARR,REL,++ep);

    // ---- Stage H: z3 assemble + LN + logits (LDS GEMV, e-split) + packed argmax ----
    {
      float* outn=sm; float* redv=sm+256; float* pp=sm+512;
      float z = bo[256+t] + R2[n*256+t];
#pragma unroll
      for (int h2=0;h2<8;h2++) z += Z3P[h2*256+t];
      float s=wredsum(z), sq2=wredsum(z*z);
      int lane=t&63, wid=t>>6;
      if (lane==0){ redv[wid]=s; redv[4+wid]=sq2; }
      __syncthreads();
      float ts=redv[0]+redv[1]+redv[2]+redv[3];
      float tq=redv[4]+redv[5]+redv[6]+redv[7];
      float mu=ts*(1.f/256.f);
      float var=tq*(1.f/256.f)-mu*mu;
      float rstd=1.f/sqrtf(var+1e-5f);
      outn[t]=(z-mu)*rstd*lng[256+t]+lnb[256+t];
      __syncthreads();
      const int c = t & 127, half = t >> 7;
      float acc = 0.f;
      if (c < 125){
        const int e0 = half*128;
#pragma unroll 8
        for (int e=e0; e<e0+128; e++) acc += outn[e]*swl[e*128+c];
      }
      if (half==1 && c<125) pp[c]=acc;
      __syncthreads();
      unsigned long long key=0ull;
      if (half==0 && c<125){
        int v=g*125+c;
        float a2 = acc + pp[c] + sb[v];
        unsigned int fb=__float_as_uint(a2);
        fb = (fb&0x80000000u)? ~fb : (fb|0x80000000u);
        key=(((unsigned long long)fb)<<32) | (unsigned long long)(~(unsigned int)v);
      }
#pragma unroll
      for (int m=32;m;m>>=1){
        unsigned long long o=shflx64(key,m);
        key = (o>key)? o : key;
      }
      if (lane==0) redU[wid]=key;
      __syncthreads();
      if (t==0){
        unsigned long long kk=redU[0];
        if (redU[1]>kk) kk=redU[1];
        if (redU[2]>kk) kk=redU[2];
        if (redU[3]>kk) kk=redU[3];
        atomicMax(SLOT, kk);
      }
    }
    gbar(ARR,REL,++ep);
  }

  // epilogue: final winner
  if (g==0 && t==0){
    unsigned long long s=__hip_atomic_load(SLOT,__ATOMIC_RELAXED,__HIP_MEMORY_SCOPE_AGENT);
    out[63]=(int)(~(unsigned int)(s&0xffffffffull));
  }
}

extern "C" void kernel_launch(void* const* d_in, const int* in_sizes, int n_in,
                              void* d_out, int out_size, void* d_ws, size_t ws_size,
                              hipStream_t stream)
{
  (void)in_sizes; (void)n_in; (void)out_size; (void)ws_size;
  hipLaunchKernelGGL(gen18124_kernel, dim3(NWG), dim3(NT), 131072, stream,
    (const float*)d_in[0],  (const float*)d_in[1],  (const float*)d_in[2],
    (const float*)d_in[3],  (const float*)d_in[4],  (const float*)d_in[5],
    (const float*)d_in[6],  (const float*)d_in[7],  (const float*)d_in[8],
    (const float*)d_in[9],  (const float*)d_in[10], (const float*)d_in[11],
    (const float*)d_in[12], (const float*)d_in[13], (const float*)d_in[14],
    (const float*)d_in[15], (int*)d_out, (float*)d_ws);
}

// Round 3
// 4291.323 us; speedup vs baseline: 3.5841x; 1.0850x over previous
//
#include <hip/hip_runtime.h>
#include <stdint.h>

// Persistent-kernel autoregressive decode for Generator_18124761989654.
// R2 -> R3 changes:
//  (1) ALL cross-WG communication (Yg,R1,QB,KB,VB,R2,Z2P,Z3P) now uses relaxed
//      agent-scope atomics (sc0/sc1 flagged, coherent at Infinity Cache).
//  (2) Loop barrier is fence-free: no buffer_wbl2 / buffer_inv per barrier.
//      __syncthreads drains vmcnt (sc1 stores LLC-visible) before the arrive
//      flag; readers use sc1 loads. Per-XCD L2 stays warm for weights all run.
//  Prelude keeps the fenced barrier (tables written with normal cached stores).

#define NWG 128
#define NT 256

__device__ __forceinline__ float ld_c(const float* p){
  return __hip_atomic_load(p, __ATOMIC_RELAXED, __HIP_MEMORY_SCOPE_AGENT);
}
__device__ __forceinline__ void st_c(float* p, float v){
  __hip_atomic_store(p, v, __ATOMIC_RELAXED, __HIP_MEMORY_SCOPE_AGENT);
}

__device__ __forceinline__ float wredsum(float v){
#pragma unroll
  for (int m=32;m;m>>=1) v += __shfl_xor(v,m,64);
  return v;
}
__device__ __forceinline__ float wredmax(float v){
#pragma unroll
  for (int m=32;m;m>>=1) v = fmaxf(v,__shfl_xor(v,m,64));
  return v;
}
__device__ __forceinline__ float g32sum(float v){
#pragma unroll
  for (int m=16;m;m>>=1) v += __shfl_xor(v,m,64);
  return v;
}
__device__ __forceinline__ float g32max(float v){
#pragma unroll
  for (int m=16;m;m>>=1) v = fmaxf(v,__shfl_xor(v,m,64));
  return v;
}
__device__ __forceinline__ unsigned long long shflx64(unsigned long long v,int m){
  unsigned int lo=(unsigned int)(v&0xffffffffull), hi=(unsigned int)(v>>32);
  lo=__shfl_xor(lo,m,64); hi=__shfl_xor(hi,m,64);
  return (((unsigned long long)hi)<<32)|(unsigned long long)lo;
}

__device__ __forceinline__ float pe_val(int l, int e){
  int j = e >> 1;
  float dv = expf((float)(2*j) * (-0.035977892078031970f));
  float arg = (float)l * dv;
  return (e & 1) ? cosf(arg) : sinf(arg);
}

// fenced barrier (prelude only): publishes normal cached stores
__device__ __forceinline__ void gbar_f(int* arr, int* rel, int ep){
  __syncthreads();
  if (threadIdx.x==0){
    __builtin_amdgcn_fence(__ATOMIC_RELEASE, "agent");
    __hip_atomic_store(arr + blockIdx.x*16, ep, __ATOMIC_RELAXED, __HIP_MEMORY_SCOPE_AGENT);
  }
  if (blockIdx.x==0){
    if (threadIdx.x < NWG){
      while (__hip_atomic_load(arr + threadIdx.x*16, __ATOMIC_RELAXED, __HIP_MEMORY_SCOPE_AGENT) != ep)
        __builtin_amdgcn_s_sleep(1);
    }
    __syncthreads();
    if (threadIdx.x==0)
      __hip_atomic_store(rel, ep, __ATOMIC_RELAXED, __HIP_MEMORY_SCOPE_AGENT);
  }
  if (threadIdx.x==0){
    while (__hip_atomic_load(rel, __ATOMIC_RELAXED, __HIP_MEMORY_SCOPE_AGENT) != ep)
      __builtin_amdgcn_s_sleep(1);
    __builtin_amdgcn_fence(__ATOMIC_ACQUIRE, "agent");
  }
  __syncthreads();
}

// fence-free barrier (decode loop): all cross-WG data moves via sc1 atomics,
// __syncthreads drains vmcnt so sc1 stores are LLC-visible before arrive.
__device__ __forceinline__ void gbar_nf(int* arr, int* rel, int ep){
  __syncthreads();
  if (threadIdx.x==0)
    __hip_atomic_store(arr + blockIdx.x*16, ep, __ATOMIC_RELAXED, __HIP_MEMORY_SCOPE_AGENT);
  if (blockIdx.x==0){
    if (threadIdx.x < NWG){
      while (__hip_atomic_load(arr + threadIdx.x*16, __ATOMIC_RELAXED, __HIP_MEMORY_SCOPE_AGENT) != ep)
        __builtin_amdgcn_s_sleep(1);
    }
    __syncthreads();
    if (threadIdx.x==0)
      __hip_atomic_store(rel, ep, __ATOMIC_RELAXED, __HIP_MEMORY_SCOPE_AGENT);
  }
  if (threadIdx.x==0){
    while (__hip_atomic_load(rel, __ATOMIC_RELAXED, __HIP_MEMORY_SCOPE_AGENT) != ep)
      __builtin_amdgcn_s_sleep(1);
  }
  __syncthreads();
}

extern "C" __global__ __launch_bounds__(256, 2)
void gen18124_kernel(const float* __restrict__ noise,
                     const float* __restrict__ iw, const float* __restrict__ ib,
                     const float* __restrict__ Wq, const float* __restrict__ bq,
                     const float* __restrict__ Wk, const float* __restrict__ bk,
                     const float* __restrict__ Wv, const float* __restrict__ bv,
                     const float* __restrict__ Wo, const float* __restrict__ bo,
                     const float* __restrict__ lng, const float* __restrict__ lnb,
                     const float* __restrict__ emb, const float* __restrict__ sw,
                     const float* __restrict__ sb,
                     int* __restrict__ out, float* __restrict__ ws)
{
  const float ISQ = 0.17677669529663687f; // 1/sqrt(32)
  __shared__ float sm[5376];
  __shared__ unsigned long long redU[4];
  extern __shared__ float swl[];          // [256][128] soft_W slice, 128KB

  // ---- workspace layout (floats) ----
  float* WVEC = ws;            // 64
  float* SKC  = ws+64;         // [2][256] colsum(Wk)
  float* SVC  = ws+576;        // [2][256] colsum(Wv)
  float* KAP  = ws+1088;       // [2][8][256]
  float* UT   = ws+5184;       // [2][8][256]
  float* CC   = ws+9280;       // [2][256]
  float* BETA = ws+9792;       // [2][8]
  unsigned long long* SLOT = (unsigned long long*)(ws+9808);
  int* ARR = (int*)(ws+9824);  // 128 * stride16 ints
  int* REL = (int*)(ws+11872);
  float* Yg  = ws+11876;       // [64][256]
  float* R1  = ws+28260;       // [64][256]
  float* QB  = ws+44644;       // [64][256]
  float* KB  = ws+61028;       // [64][256]
  float* VB  = ws+77412;       // [64][256]
  float* R2  = ws+93796;       // [64][256]
  float* Z2P = ws+110180;      // [8][64][256]
  float* Z3P = ws+241252;      // [8][256]

  const int g = blockIdx.x, t = threadIdx.x;
  int ep = 0;

  // ---- soft_W slice -> LDS (WG-private, no barrier needed) ----
  {
    const int base = g*125;
#pragma unroll 8
    for (int i=t; i<256*128; i+=NT){
      int e=i>>7, c=i&127;
      float val = 0.f;
      if (c<125) val = sw[e*16000 + base + c];
      swl[i]=val;
    }
  }

  // ================= Prelude A: colsums, wvec, Y0, slot/out init =================
  {
    int c0 = 2*g;
    float a0=Wk[t*256+c0],       a1=Wk[t*256+c0+1];
    float a2=Wk[65536+t*256+c0], a3=Wk[65536+t*256+c0+1];
    float a4=Wv[t*256+c0],       a5=Wv[t*256+c0+1];
    float a6=Wv[65536+t*256+c0], a7=Wv[65536+t*256+c0+1];
    a0=wredsum(a0); a1=wredsum(a1); a2=wredsum(a2); a3=wredsum(a3);
    a4=wredsum(a4); a5=wredsum(a5); a6=wredsum(a6); a7=wredsum(a7);
    int lane=t&63, wid=t>>6;
    if (lane==0){
      sm[wid*8+0]=a0; sm[wid*8+1]=a1; sm[wid*8+2]=a2; sm[wid*8+3]=a3;
      sm[wid*8+4]=a4; sm[wid*8+5]=a5; sm[wid*8+6]=a6; sm[wid*8+7]=a7;
    }
    __syncthreads();
    if (t<8){
      float s=sm[t]+sm[8+t]+sm[16+t]+sm[24+t];
      if (t<4) SKC[(t>>1)*256 + c0 + (t&1)] = s;
      else     SVC[((t-4)>>1)*256 + c0 + ((t-4)&1)] = s;
    }
    __syncthreads();
    if (g==0){
      float* wl = sm+64;
      if (t<64) wl[t] = noise[t];
      __syncthreads();
      for (int i=0;i<4;i++){
        float acc=0.f;
        if (t<64){
          for (int in_=0;in_<64;in_++) acc += wl[in_]*iw[(i*64+in_)*64+t];
          acc += ib[i*64+t];
        }
        __syncthreads();
        if (t<64) wl[t]=acc;
        __syncthreads();
      }
      if (t<64) WVEC[t]=wl[t];
      if (t==0) *SLOT = 0ull;
    }
    if (g==1){
      Yg[t] = emb[t] + pe_val(0,t);   // normal store; published by fenced prelude barriers
      if (t==0) out[0]=0;
    }
  }
  gbar_f(ARR,REL,++ep);

  // ================= Prelude B: KAP / UT / CC / BETA tables =================
  {
    int c0 = 2*g;
    float p00 = bv[t]    *Wo[t*256+c0],        p01 = bv[t]    *Wo[t*256+c0+1];
    float p10 = bv[256+t]*Wo[65536+t*256+c0],  p11 = bv[256+t]*Wo[65536+t*256+c0+1];
    p00=wredsum(p00); p01=wredsum(p01); p10=wredsum(p10); p11=wredsum(p11);
    int lane=t&63, wid=t>>6;
    if (lane==0){ sm[wid*4+0]=p00; sm[wid*4+1]=p01; sm[wid*4+2]=p10; sm[wid*4+3]=p11; }
    __syncthreads();
    if (t<4){
      float s=sm[t]+sm[4+t]+sm[8+t]+sm[12+t];
      int i=t>>1, cl=t&1;
      CC[i*256+c0+cl] = s + bo[i*256+c0+cl];
    }
    if (t<32){
      int i=t>>4, h=(t>>1)&7, c=c0+(t&1);
      float s=0.f;
      for (int e2=0;e2<32;e2++) s += SVC[i*256+h*32+e2]*Wo[i*65536+(h*32+e2)*256+c];
      UT[(i*8+h)*256+c]=s;
    }
    if (t>=32 && t<64){
      int u=t-32, i=u>>4, h=(u>>1)&7, e=c0+(u&1);
      float s=0.f;
      for (int c2=0;c2<32;c2++) s += Wq[i*65536+e*256+h*32+c2]*SKC[i*256+h*32+c2];
      KAP[(i*8+h)*256+e]=s;
    }
    if (g==0 && t>=64 && t<80){
      int u=t-64, i=u>>3, h=u&7;
      float s=0.f;
      for (int c2=0;c2<32;c2++) s += bq[i*256+h*32+c2]*SKC[i*256+h*32+c2];
      BETA[i*8+h]=s;
    }
  }
  gbar_f(ARR,REL,++ep);

  // ================= decode loop (fence-free barriers, sc1 communication) ======
  for (int tok=1; tok<64; tok++){
    const int n = tok-1;

    // ---- Stage A: WG-per-row, both cross blocks (rank-1 collapsed) -> r1 ----
    if (g < tok){
      const int q = g;
      float* xrow = sm; float* rrow = sm+256; float* m8 = sm+512; float* redv = sm+528;
      if (q==n && tok>1){
        unsigned long long s = __hip_atomic_load(SLOT, __ATOMIC_RELAXED, __HIP_MEMORY_SCOPE_AGENT);
        int v = (int)(~(unsigned int)(s & 0xffffffffull));
        if (t==0) out[q]=v;
        float yv = emb[v*256+t] + pe_val(q,t);
        xrow[t]=yv; st_c(&Yg[q*256+t], yv);
      } else {
        xrow[t]=ld_c(&Yg[q*256+t]);
      }
      __syncthreads();
      for (int blk=0; blk<2; blk++){
        const float* src = blk ? rrow : xrow;
        int h=t>>5, j=t&31;
        float part=0.f;
        for (int jj=j; jj<256; jj+=32) part += src[jj]*KAP[(blk*8+h)*256+jj];
        part = g32sum(part);
        float alpha = (part + BETA[blk*8+h]) * ISQ;
        float s1 = (j<tok)     ? alpha*WVEC[j]    : -3.4e38f;
        float s2 = (j+32<tok)  ? alpha*WVEC[j+32] : -3.4e38f;
        float mx = g32max(fmaxf(s1,s2));
        float e1 = expf(s1-mx), e2 = expf(s2-mx);
        float sn = e1*((j<tok)?WVEC[j]:0.f) + e2*((j+32<tok)?WVEC[j+32]:0.f);
        float sd = e1+e2;
        sn=g32sum(sn); sd=g32sum(sd);
        if (j==0) m8[h]=sn/sd;
        __syncthreads();
        float x_ = blk ? rrow[t] : xrow[t];
        float z = CC[blk*256+t] + x_;
#pragma unroll
        for (int h2=0;h2<8;h2++) z += m8[h2]*UT[(blk*8+h2)*256+t];
        float ssum=wredsum(z), ssq=wredsum(z*z);
        int lane=t&63, wid=t>>6;
        if (lane==0){ redv[wid]=ssum; redv[4+wid]=ssq; }
        __syncthreads();
        float ts=redv[0]+redv[1]+redv[2]+redv[3];
        float tq=redv[4]+redv[5]+redv[6]+redv[7];
        float mu=ts*(1.f/256.f);
        float var=tq*(1.f/256.f)-mu*mu;
        float rstd=1.f/sqrtf(var+1e-5f);
        float rv=(z-mu)*rstd*lng[blk*256+t]+lnb[blk*256+t];
        __syncthreads();
        rrow[t]=rv;
        __syncthreads();
      }
      st_c(&R1[q*256+t], rrow[t]);
    }
    gbar_nf(ARR,REL,++ep);

    // ---- Stage B: self0 Q/K/V projection, (rowgroup, head) mapping ----
    {
      if (g==0 && t==0) __hip_atomic_store(SLOT, 0ull, __ATOMIC_RELAXED, __HIP_MEMORY_SCOPE_AGENT);
      const int h=g&7, rg=g>>3;
      float* rows4 = sm; // [4][256]
#pragma unroll
      for (int jj=0;jj<4;jj++) rows4[jj*256+t] = ld_c(&R1[(rg+16*jj)*256+t]);
      __syncthreads();
      int c=t&31, epp=t>>5;
      const int col=h*32+c;
      float aq[4]={0,0,0,0}, ak[4]={0,0,0,0}, av[4]={0,0,0,0};
#pragma unroll 8
      for (int e=epp*32; e<epp*32+32; e++){
        float wq_=Wq[e*256+col], wk_=Wk[e*256+col], wv_=Wv[e*256+col];
#pragma unroll
        for (int jj=0;jj<4;jj++){ float r=rows4[jj*256+e]; aq[jj]+=r*wq_; ak[jj]+=r*wk_; av[jj]+=r*wv_; }
      }
#pragma unroll
      for (int jj=0;jj<4;jj++){
        aq[jj]+=__shfl_xor(aq[jj],32,64);
        ak[jj]+=__shfl_xor(ak[jj],32,64);
        av[jj]+=__shfl_xor(av[jj],32,64);
      }
      float4* redq=(float4*)(sm+1056); float4* redk=(float4*)(sm+1568); float4* redv4=(float4*)(sm+2080);
      int lane=t&63, wid=t>>6;
      if (lane<32){
        redq[wid*32+lane]=make_float4(aq[0],aq[1],aq[2],aq[3]);
        redk[wid*32+lane]=make_float4(ak[0],ak[1],ak[2],ak[3]);
        redv4[wid*32+lane]=make_float4(av[0],av[1],av[2],av[3]);
      }
      __syncthreads();
      if (t<32){
        float4 A=redq[t],B4=redq[32+t],C4=redq[64+t],D4=redq[96+t];
        float sq[4]={A.x+B4.x+C4.x+D4.x, A.y+B4.y+C4.y+D4.y, A.z+B4.z+C4.z+D4.z, A.w+B4.w+C4.w+D4.w};
        A=redk[t];B4=redk[32+t];C4=redk[64+t];D4=redk[96+t];
        float sk[4]={A.x+B4.x+C4.x+D4.x, A.y+B4.y+C4.y+D4.y, A.z+B4.z+C4.z+D4.z, A.w+B4.w+C4.w+D4.w};
        A=redv4[t];B4=redv4[32+t];C4=redv4[64+t];D4=redv4[96+t];
        float sv[4]={A.x+B4.x+C4.x+D4.x, A.y+B4.y+C4.y+D4.y, A.z+B4.z+C4.z+D4.z, A.w+B4.w+C4.w+D4.w};
        int cc=h*32+t;
        float bq_=bq[cc], bk_=bk[cc], bv_=bv[cc];
#pragma unroll
        for (int jj=0;jj<4;jj++){
          int q_=rg+16*jj;
          if (q_<tok){
            st_c(&QB[q_*256+cc], sq[jj]+bq_);
            st_c(&KB[q_*256+cc], sk[jj]+bk_);
            st_c(&VB[q_*256+cc], sv[jj]+bv_);
          }
        }
      }
    }
    gbar_nf(ARR,REL,++ep);

    // ---- Stage C: self0 attention + per-head partial O-proj -> Z2P ----
    {
      const int h=g&7, rg=g>>3;
      float* Ks=sm; float* Vs=sm+2112; float* qrow=sm+4224; float* arow=sm+4352; float* o2s=sm+4608;
      int k=t>>2, f0=(t&3)*8;
      if (k<tok){
#pragma unroll
        for (int i2=0;i2<8;i2++){
          Ks[k*33+f0+i2]=ld_c(&KB[k*256+h*32+f0+i2]);
          Vs[k*33+f0+i2]=ld_c(&VB[k*256+h*32+f0+i2]);
        }
      }
      if (t<128){ int jj=t>>5, c=t&31; int q_=rg+16*jj; if (q_<tok) qrow[jj*32+c]=ld_c(&QB[q_*256+h*32+c]); }
      __syncthreads();
      int w=t>>6, lane=t&63; int q_=rg+16*w; bool ok=q_<tok;
      float sc=-3.4e38f;
      if (ok && lane<tok){
        sc=0.f;
#pragma unroll
        for (int c2=0;c2<32;c2++) sc+=qrow[w*32+c2]*Ks[lane*33+c2];
        sc*=ISQ;
      }
      float mx=wredmax(sc);
      float ex=(ok&&lane<tok)? expf(sc-mx):0.f;
      float sd=wredsum(ex);
      arow[w*64+lane]= ok ? ex/sd : 0.f;
      __syncthreads();
      int j=lane&31, half=lane>>5;
      float oa=0.f;
      if (ok){ for (int k2=half;k2<tok;k2+=2) oa+=arow[w*64+k2]*Vs[k2*33+j]; }
      oa += __shfl_xor(oa,32,64);
      if (lane<32) o2s[w*32+j]=oa;
      __syncthreads();
      float acc[4]={0,0,0,0};
#pragma unroll 8
      for (int j2=0;j2<32;j2++){
        float wv_=Wo[(h*32+j2)*256+t];
#pragma unroll
        for (int jj=0;jj<4;jj++) acc[jj]+=o2s[jj*32+j2]*wv_;
      }
#pragma unroll
      for (int jj=0;jj<4;jj++){ int q2=rg+16*jj; if (q2<tok) st_c(&Z2P[(h*64+q2)*256+t], acc[jj]); }
    }
    gbar_nf(ARR,REL,++ep);

    // ---- Stage E: z2 assemble + LN -> r2 ; self1 K/V proj (+Q for row n) ----
    {
      const int h=g&7, rg=g>>3;
      float* rows4=sm; float* mus=sm+1024;
#pragma unroll
      for (int jj=0;jj<4;jj++){
        int q_=rg+16*jj;
        float z = bo[t] + ld_c(&R1[q_*256+t]);
#pragma unroll
        for (int h2=0;h2<8;h2++) z += ld_c(&Z2P[(h2*64+q_)*256+t]);
        rows4[jj*256+t]=z;
      }
      __syncthreads();
      {
        int w=t>>6, lane=t&63;
        float v0=rows4[w*256+lane], v1=rows4[w*256+64+lane], v2=rows4[w*256+128+lane], v3=rows4[w*256+192+lane];
        float s=v0+v1+v2+v3, sq2=v0*v0+v1*v1+v2*v2+v3*v3;
        s=wredsum(s); sq2=wredsum(sq2);
        if (lane==0){
          float mu=s*(1.f/256.f);
          float var=sq2*(1.f/256.f)-mu*mu;
          mus[w*2]=mu; mus[w*2+1]=1.f/sqrtf(var+1e-5f);
        }
      }
      __syncthreads();
#pragma unroll
      for (int jj=0;jj<4;jj++){
        float mu=mus[jj*2], rstd=mus[jj*2+1];
        float val=(rows4[jj*256+t]-mu)*rstd*lng[t]+lnb[t];
        rows4[jj*256+t]=val;
        int q_=rg+16*jj;
        if (h==0 && q_<tok) st_c(&R2[q_*256+t], val);
      }
      __syncthreads();
      int c=t&31, epp=t>>5;
      const int col=h*32+c;
      float aq[4]={0,0,0,0}, ak[4]={0,0,0,0}, av[4]={0,0,0,0};
#pragma unroll 8
      for (int e=epp*32; e<epp*32+32; e++){
        float wq_=Wq[65536+e*256+col], wk_=Wk[65536+e*256+col], wv_=Wv[65536+e*256+col];
#pragma unroll
        for (int jj=0;jj<4;jj++){ float r=rows4[jj*256+e]; aq[jj]+=r*wq_; ak[jj]+=r*wk_; av[jj]+=r*wv_; }
      }
#pragma unroll
      for (int jj=0;jj<4;jj++){
        aq[jj]+=__shfl_xor(aq[jj],32,64);
        ak[jj]+=__shfl_xor(ak[jj],32,64);
        av[jj]+=__shfl_xor(av[jj],32,64);
      }
      float4* redq=(float4*)(sm+1056); float4* redk=(float4*)(sm+1568); float4* redv4=(float4*)(sm+2080);
      int lane=t&63, wid=t>>6;
      if (lane<32){
        redq[wid*32+lane]=make_float4(aq[0],aq[1],aq[2],aq[3]);
        redk[wid*32+lane]=make_float4(ak[0],ak[1],ak[2],ak[3]);
        redv4[wid*32+lane]=make_float4(av[0],av[1],av[2],av[3]);
      }
      __syncthreads();
      if (t<32){
        float4 A=redq[t],B4=redq[32+t],C4=redq[64+t],D4=redq[96+t];
        float sq[4]={A.x+B4.x+C4.x+D4.x, A.y+B4.y+C4.y+D4.y, A.z+B4.z+C4.z+D4.z, A.w+B4.w+C4.w+D4.w};
        A=redk[t];B4=redk[32+t];C4=redk[64+t];D4=redk[96+t];
        float sk[4]={A.x+B4.x+C4.x+D4.x, A.y+B4.y+C4.y+D4.y, A.z+B4.z+C4.z+D4.z, A.w+B4.w+C4.w+D4.w};
        A=redv4[t];B4=redv4[32+t];C4=redv4[64+t];D4=redv4[96+t];
        float sv[4]={A.x+B4.x+C4.x+D4.x, A.y+B4.y+C4.y+D4.y, A.z+B4.z+C4.z+D4.z, A.w+B4.w+C4.w+D4.w};
        int cc=h*32+t;
#pragma unroll
        for (int jj=0;jj<4;jj++){
          int q_=rg+16*jj;
          if (q_<tok){
            st_c(&KB[q_*256+cc], sk[jj]+bk[256+cc]);
            st_c(&VB[q_*256+cc], sv[jj]+bv[256+cc]);
            if (q_==n) st_c(&QB[q_*256+cc], sq[jj]+bq[256+cc]);
          }
        }
      }
    }
    gbar_nf(ARR,REL,++ep);

    // ---- Stage F: self1 attention for row n only + per-head partial O-proj -> Z3P ----
    {
      const int h=g&7, rg=g>>3;
      if (rg == (n&15)){
        float* Ks=sm; float* Vs=sm+2112; float* qn=sm+4224; float* arow=sm+4352; float* o3s=sm+4608;
        int k=t>>2, f0=(t&3)*8;
        if (k<tok){
#pragma unroll
          for (int i2=0;i2<8;i2++){
            Ks[k*33+f0+i2]=ld_c(&KB[k*256+h*32+f0+i2]);
            Vs[k*33+f0+i2]=ld_c(&VB[k*256+h*32+f0+i2]);
          }
        }
        if (t<32) qn[t]=ld_c(&QB[n*256+h*32+t]);
        __syncthreads();
        int lane=t&63, w=t>>6;
        if (w==0){
          float sc=-3.4e38f;
          if (lane<tok){
            sc=0.f;
#pragma unroll
            for (int c2=0;c2<32;c2++) sc+=qn[c2]*Ks[lane*33+c2];
            sc*=ISQ;
          }
          float mx=wredmax(sc);
          float ex=(lane<tok)? expf(sc-mx):0.f;
          float sd=wredsum(ex);
          arow[lane]=ex/sd;
        }
        __syncthreads();
        if (w==0){
          int j=lane&31, half=lane>>5;
          float oa=0.f;
          for (int k2=half;k2<tok;k2+=2) oa+=arow[k2]*Vs[k2*33+j];
          oa+=__shfl_xor(oa,32,64);
          if (lane<32) o3s[j]=oa;
        }
        __syncthreads();
        float acc=0.f;
#pragma unroll 8
        for (int j2=0;j2<32;j2++) acc+=o3s[j2]*Wo[65536+(h*32+j2)*256+t];
        st_c(&Z3P[h*256+t], acc);
      }
    }
    gbar_nf(ARR,REL,++ep);

    // ---- Stage H: z3 assemble + LN + logits (LDS GEMV, e-split) + packed argmax ----
    {
      float* outn=sm; float* redv=sm+256; float* pp=sm+512;
      float z = bo[256+t] + ld_c(&R2[n*256+t]);
#pragma unroll
      for (int h2=0;h2<8;h2++) z += ld_c(&Z3P[h2*256+t]);
      float s=wredsum(z), sq2=wredsum(z*z);
      int lane=t&63, wid=t>>6;
      if (lane==0){ redv[wid]=s; redv[4+wid]=sq2; }
      __syncthreads();
      float ts=redv[0]+redv[1]+redv[2]+redv[3];
      float tq=redv[4]+redv[5]+redv[6]+redv[7];
      float mu=ts*(1.f/256.f);
      float var=tq*(1.f/256.f)-mu*mu;
      float rstd=1.f/sqrtf(var+1e-5f);
      outn[t]=(z-mu)*rstd*lng[256+t]+lnb[256+t];
      __syncthreads();
      const int c = t & 127, half = t >> 7;
      float acc = 0.f;
      if (c < 125){
        const int e0 = half*128;
#pragma unroll 8
        for (int e=e0; e<e0+128; e++) acc += outn[e]*swl[e*128+c];
      }
      if (half==1 && c<125) pp[c]=acc;
      __syncthreads();
      unsigned long long key=0ull;
      if (half==0 && c<125){
        int v=g*125+c;
        float a2 = acc + pp[c] + sb[v];
        unsigned int fb=__float_as_uint(a2);
        fb = (fb&0x80000000u)? ~fb : (fb|0x80000000u);
        key=(((unsigned long long)fb)<<32) | (unsigned long long)(~(unsigned int)v);
      }
#pragma unroll
      for (int m=32;m;m>>=1){
        unsigned long long o=shflx64(key,m);
        key = (o>key)? o : key;
      }
      if (lane==0) redU[wid]=key;
      __syncthreads();
      if (t==0){
        unsigned long long kk=redU[0];
        if (redU[1]>kk) kk=redU[1];
        if (redU[2]>kk) kk=redU[2];
        if (redU[3]>kk) kk=redU[3];
        atomicMax(SLOT, kk);
      }
    }
    gbar_nf(ARR,REL,++ep);
  }

  // epilogue: final winner
  if (g==0 && t==0){
    unsigned long long s=__hip_atomic_load(SLOT,__ATOMIC_RELAXED,__HIP_MEMORY_SCOPE_AGENT);
    out[63]=(int)(~(unsigned int)(s&0xffffffffull));
  }
}

extern "C" void kernel_launch(void* const* d_in, const int* in_sizes, int n_in,
                              void* d_out, int out_size, void* d_ws, size_t ws_size,
                              hipStream_t stream)
{
  (void)in_sizes; (void)n_in; (void)out_size; (void)ws_size;
  hipLaunchKernelGGL(gen18124_kernel, dim3(NWG), dim3(NT), 131072, stream,
    (const float*)d_in[0],  (const float*)d_in[1],  (const float*)d_in[2],
    (const float*)d_in[3],  (const float*)d_in[4],  (const float*)d_in[5],
    (const float*)d_in[6],  (const float*)d_in[7],  (const float*)d_in[8],
    (const float*)d_in[9],  (const float*)d_in[10], (const float*)d_in[11],
    (const float*)d_in[12], (const float*)d_in[13], (const float*)d_in[14],
    (const float*)d_in[15], (int*)d_out, (float*)d_ws);
}